// Round 1
// baseline (42.790 us; speedup 1.0000x reference)
//
#include <hip/hip_runtime.h>
#include <math.h>

// Problem constants (verified against setup_inputs): E=1024, CTX=1024.
#define EDIM 1024
#define CTXDIM 1024
#define H2 2048

// ws layout (floats):
//   [0    : 2048)  h
//   [2048 : 3072)  mu
//   [3072 : 4096)  sigma
//   [4096]         logdet = sum(log(sigma))
//   [4100 : 4100+1+C+C*NEG)  S values: S[0]=S_x, S[1..C]=pos, S[C+1..]=neg

// ---------------- Kernel 1: h[2048] ----------------
// grid 128 blocks x 256 thr. Each block: 8 output columns j, 32 threads/col.
// M_w[j] held in registers (8 x float4 / thread); emb row staged in LDS.
__global__ __launch_bounds__(256) void k_h(
    const float* __restrict__ emb, const float* __restrict__ Mw,
    const float* __restrict__ Mb, const int* __restrict__ x,
    const int* __restrict__ ctx, int C, float* __restrict__ ws)
{
    __shared__ float4 rowbuf[256];                 // one emb row (1024 f32)
    const int tid = threadIdx.x;
    const int jl  = tid >> 5;                      // 0..7 local column
    const int p   = tid & 31;                      // 0..31 pos in column group
    const int j   = blockIdx.x * 8 + jl;           // 0..1023

    float4 mw[8];
    const float4* mrow = (const float4*)(Mw + (size_t)j * EDIM);
#pragma unroll
    for (int k = 0; k < 8; ++k) mw[k] = mrow[p + 32 * k];

    const float bj = Mb[j];
    float rw = 0.f, acc = 0.f;

    for (int r = 0; r <= C; ++r) {
        const int idx = (r == 0) ? x[0] : ctx[r - 1];
        __syncthreads();
        rowbuf[tid] = ((const float4*)(emb + (size_t)idx * EDIM))[tid];
        __syncthreads();
        float s = 0.f;
#pragma unroll
        for (int k = 0; k < 8; ++k) {
            const float4 rv = rowbuf[p + 32 * k];
            s += rv.x * mw[k].x + rv.y * mw[k].y + rv.z * mw[k].z + rv.w * mw[k].w;
        }
#pragma unroll
        for (int m = 16; m >= 1; m >>= 1) s += __shfl_xor(s, m);
        const float v = fmaxf(s + bj, 0.f);
        if (r == 0) rw = v; else acc += v;
    }

    if (p == 0) {
        ws[j]          = (float)C * rw;   // Rw broadcast to C rows, relu, sum
        ws[CTXDIM + j] = acc;             // sum_c relu(Rc)
    }
}

// ---------------- Kernel 2: mu, sigma ----------------
// grid 512 x 256. One wave per output row (2048 rows: 1024 mu + 1024 sigma).
__global__ __launch_bounds__(256) void k_musig(
    const float* __restrict__ Uw, const float* __restrict__ Ub,
    const float* __restrict__ Ww, const float* __restrict__ Wb,
    float* __restrict__ ws)
{
    __shared__ float4 hbuf[512];                   // h (2048 f32)
    const int tid = threadIdx.x;
    const float4* hg = (const float4*)ws;
    hbuf[tid]       = hg[tid];
    hbuf[tid + 256] = hg[tid + 256];
    __syncthreads();

    const int w = tid >> 6, lane = tid & 63;
    const int r = blockIdx.x * 4 + w;              // 0..2047
    const bool is_mu = (r < CTXDIM);
    const int rr = is_mu ? r : r - CTXDIM;
    const float4* Wr4 = (const float4*)((is_mu ? Uw : Ww) + (size_t)rr * H2);

    float s = 0.f;
#pragma unroll
    for (int k = 0; k < 8; ++k) {
        const float4 wv = Wr4[lane + 64 * k];
        const float4 hv = hbuf[lane + 64 * k];
        s += wv.x * hv.x + wv.y * hv.y + wv.z * hv.z + wv.w * hv.w;
    }
#pragma unroll
    for (int m = 32; m >= 1; m >>= 1) s += __shfl_xor(s, m);

    if (lane == 0) {
        if (is_mu) {
            ws[2048 + rr] = s + Ub[rr];
        } else {
            const float v = s + Wb[rr];
            // softplus, numerically safe
            ws[3072 + rr] = fmaxf(v, 0.f) + log1pf(expf(-fabsf(v)));
        }
    }
}

// ---------------- Kernel 3a: S(idx) per candidate + logdet ----------------
// One wave per task. task 0: logdet; task 1: x; tasks [2,2+C): pos;
// tasks [2+C, 2+C+CN): neg (row-major flatten of neg_samples).
__global__ __launch_bounds__(256) void k_S(
    const float* __restrict__ pmu, const float* __restrict__ psig,
    const int* __restrict__ x, const int* __restrict__ ctx,
    const int* __restrict__ negs, int C, int CN, float* __restrict__ ws)
{
    const int tid = threadIdx.x;
    const int w = tid >> 6, lane = tid & 63;
    const int t = blockIdx.x * 4 + w;
    const int ntask = 2 + C + CN;
    if (t >= ntask) return;

    if (t == 0) {   // logdet = sum log sigma
        float s = 0.f;
#pragma unroll
        for (int k = 0; k < 16; ++k) s += logf(ws[3072 + lane + 64 * k]);
#pragma unroll
        for (int m = 32; m >= 1; m >>= 1) s += __shfl_xor(s, m);
        if (lane == 0) ws[4096] = s;
        return;
    }

    int idx;
    if (t == 1)           idx = x[0];
    else if (t < 2 + C)   idx = ctx[t - 2];
    else                  idx = negs[t - 2 - C];

    const float4* m4  = (const float4*)(pmu  + (size_t)idx * CTXDIM);
    const float4* s4  = (const float4*)(psig + (size_t)idx * CTXDIM);
    const float4* mu4 = (const float4*)(ws + 2048);
    const float4* sg4 = (const float4*)(ws + 3072);

    float acc = 0.f;
#pragma unroll
    for (int k = 0; k < 4; ++k) {
        const int i = lane + 64 * k;
        const float4 m  = m4[i];
        const float4 sv = s4[i];
        const float4 mu = mu4[i];
        const float4 sg = sg4[i];
        {
            const float s2 = sv.x * sv.x; const float d = m.x - mu.x;
            acc += (sg.x + d * d) / s2 + logf(s2);
        }
        {
            const float s2 = sv.y * sv.y; const float d = m.y - mu.y;
            acc += (sg.y + d * d) / s2 + logf(s2);
        }
        {
            const float s2 = sv.z * sv.z; const float d = m.z - mu.z;
            acc += (sg.z + d * d) / s2 + logf(s2);
        }
        {
            const float s2 = sv.w * sv.w; const float d = m.w - mu.w;
            acc += (sg.w + d * d) / s2 + logf(s2);
        }
    }
#pragma unroll
    for (int m = 32; m >= 1; m >>= 1) acc += __shfl_xor(acc, m);
    if (lane == 0) ws[4100 + (t - 1)] = acc;
}

// ---------------- Kernel 3b: hinge sum + final scalar ----------------
__global__ __launch_bounds__(512) void k_final(
    int C, int NEG, int KDIM, float* __restrict__ ws, float* __restrict__ out)
{
    __shared__ float part[8];
    const int tid = threadIdx.x;
    const int CN = C * NEG;
    const float* S = ws + 4100;

    float v = 0.f;
    if (tid < CN) {
        const int c = tid / NEG;
        // kl_neg - kl_pos = 0.5*(S_neg - S_pos)  (k and logdet cancel)
        v = fmaxf(0.f, 0.5f * (S[1 + C + tid] - S[1 + c]) + 1.0f);
    }
#pragma unroll
    for (int m = 32; m >= 1; m >>= 1) v += __shfl_xor(v, m);
    if ((tid & 63) == 0) part[tid >> 6] = v;
    __syncthreads();
    if (tid == 0) {
        float lik = 0.f;
#pragma unroll
        for (int i = 0; i < 8; ++i) lik += part[i];
        const float klprior = 0.5f * (S[0] - (float)KDIM - ws[4096]);
        out[0] = lik - klprior;
    }
}

extern "C" void kernel_launch(void* const* d_in, const int* in_sizes, int n_in,
                              void* d_out, int out_size, void* d_ws, size_t ws_size,
                              hipStream_t stream) {
    const int*   x    = (const int*)d_in[0];
    const int*   ctx  = (const int*)d_in[1];
    const int*   negs = (const int*)d_in[2];
    const float* emb  = (const float*)d_in[3];
    const float* Mw   = (const float*)d_in[4];
    const float* Mb   = (const float*)d_in[5];
    const float* Uw   = (const float*)d_in[6];
    const float* Ub   = (const float*)d_in[7];
    const float* Ww   = (const float*)d_in[8];
    const float* Wb   = (const float*)d_in[9];
    const float* pmu  = (const float*)d_in[10];
    const float* psig = (const float*)d_in[11];
    float* ws  = (float*)d_ws;
    float* out = (float*)d_out;

    const int C    = in_sizes[1];          // 50
    const int CN   = in_sizes[2];          // 500
    const int NEG  = CN / C;               // 10
    const int KDIM = in_sizes[5];          // CTX = 1024

    k_h<<<CTXDIM / 8, 256, 0, stream>>>(emb, Mw, Mb, x, ctx, C, ws);
    k_musig<<<512, 256, 0, stream>>>(Uw, Ub, Ww, Wb, ws);
    const int ntask = 2 + C + CN;
    k_S<<<(ntask + 3) / 4, 256, 0, stream>>>(pmu, psig, x, ctx, negs, C, CN, ws);
    k_final<<<1, 512, 0, stream>>>(C, NEG, KDIM, ws, out);
}

// Round 2
// 36.908 us; speedup vs baseline: 1.1594x; 1.1594x over previous
//
#include <hip/hip_runtime.h>
#include <math.h>

// Problem constants (verified against setup_inputs): E=1024, CTX=1024.
#define EDIM 1024
#define CTXDIM 1024
#define H2 2048

// ws float layout:
//   [0    : 1024)  h first half  = C * relu(emb[x] @ Mw^T + Mb)
//   [1024 : 2048)  h second half = sum_c relu(emb[ctx] @ Mw^T + Mb)
//   [2048 : 3072)  mu
//   [3072 : 4096)  sigma
//   ws[4099]       (unsigned) completion counter for k_S finisher
//   [4100 : 4100+2+C+CN)  S: S[0]=logdet, S[1]=S_x, S[2..2+C)=pos, S[2+C..)=neg

// ---------------- Kernel 1: h[2048] ----------------
// grid 256 x 1024 thr (16 waves). Block owns 4 output cols; wave (c,g)
// handles col 4b+c for rows r ≡ g (mod 4) of the 51 input rows (row 0 = x).
// Mw col in registers; emb rows read straight from L1/L2 (rows shared by the
// 4 same-g waves in the block). No barriers in the main loop.
__global__ __launch_bounds__(1024) void k_h(
    const float* __restrict__ emb, const float* __restrict__ Mw,
    const float* __restrict__ Mb, const int* __restrict__ x,
    const int* __restrict__ ctx, int C, float* __restrict__ ws)
{
    __shared__ float pacc[16];
    __shared__ float pxs[4];
    const int tid  = threadIdx.x;
    const int w    = tid >> 6;
    const int lane = tid & 63;
    const int c    = w & 3;          // local col
    const int g    = w >> 2;         // row group
    const int j    = blockIdx.x * 4 + c;

    const float4* mrow = (const float4*)(Mw + (size_t)j * EDIM);
    const float4 mw0 = mrow[lane];
    const float4 mw1 = mrow[lane + 64];
    const float4 mw2 = mrow[lane + 128];
    const float4 mw3 = mrow[lane + 192];
    const float bj = Mb[j];

    float acc = 0.f, px = 0.f;
    const int R = 1 + C;
    for (int r = g; r < R; r += 4) {
        const int idx = (r == 0) ? x[0] : ctx[r - 1];
        const float4* e4 = (const float4*)(emb + (size_t)idx * EDIM);
        const float4 a = e4[lane];
        const float4 b = e4[lane + 64];
        const float4 d = e4[lane + 128];
        const float4 e = e4[lane + 192];
        float s = a.x*mw0.x + a.y*mw0.y + a.z*mw0.z + a.w*mw0.w;
        s += b.x*mw1.x + b.y*mw1.y + b.z*mw1.z + b.w*mw1.w;
        s += d.x*mw2.x + d.y*mw2.y + d.z*mw2.z + d.w*mw2.w;
        s += e.x*mw3.x + e.y*mw3.y + e.z*mw3.z + e.w*mw3.w;
#pragma unroll
        for (int m = 32; m >= 1; m >>= 1) s += __shfl_xor(s, m);
        const float v = fmaxf(s + bj, 0.f);
        if (r == 0) px = (float)C * v;   // x row appears only in group 0
        else        acc += v;
    }
    if (lane == 0) {
        pacc[w] = acc;
        if (g == 0) pxs[c] = px;
    }
    __syncthreads();
    if (tid < 4) {
        const int jj = blockIdx.x * 4 + tid;
        ws[jj]           = pxs[tid];
        ws[CTXDIM + jj]  = pacc[tid] + pacc[tid + 4] + pacc[tid + 8] + pacc[tid + 12];
    }
}

// ---------------- Kernel 2: mu, sigma ----------------
// grid 512 x 256. One wave per output row (2048 rows: 1024 mu + 1024 sigma).
// Also zeroes the k_S completion counter (runs before k_S in stream order).
__global__ __launch_bounds__(256) void k_musig(
    const float* __restrict__ Uw, const float* __restrict__ Ub,
    const float* __restrict__ Ww, const float* __restrict__ Wb,
    float* __restrict__ ws)
{
    if (blockIdx.x == 0 && threadIdx.x == 0) {
        __hip_atomic_store((unsigned*)(ws + 4099), 0u,
                           __ATOMIC_RELAXED, __HIP_MEMORY_SCOPE_AGENT);
    }
    __shared__ float4 hbuf[512];                   // h (2048 f32)
    const int tid = threadIdx.x;
    const float4* hg = (const float4*)ws;
    hbuf[tid]       = hg[tid];
    hbuf[tid + 256] = hg[tid + 256];
    __syncthreads();

    const int w = tid >> 6, lane = tid & 63;
    const int r = blockIdx.x * 4 + w;              // 0..2047
    const bool is_mu = (r < CTXDIM);
    const int rr = is_mu ? r : r - CTXDIM;
    const float4* Wr4 = (const float4*)((is_mu ? Uw : Ww) + (size_t)rr * H2);

    float s = 0.f;
#pragma unroll
    for (int k = 0; k < 8; ++k) {
        const float4 wv = Wr4[lane + 64 * k];
        const float4 hv = hbuf[lane + 64 * k];
        s += wv.x * hv.x + wv.y * hv.y + wv.z * hv.z + wv.w * hv.w;
    }
#pragma unroll
    for (int m = 32; m >= 1; m >>= 1) s += __shfl_xor(s, m);

    if (lane == 0) {
        if (is_mu) {
            ws[2048 + rr] = s + Ub[rr];
        } else {
            const float v = s + Wb[rr];
            ws[3072 + rr] = fmaxf(v, 0.f) + log1pf(expf(-fabsf(v)));  // softplus
        }
    }
}

// ---------------- Kernel 3: per-candidate S + fused finale ----------------
// One wave per task. task 0: logdet; task 1: x; [2,2+C): pos; [2+C,2+C+CN): neg.
// Last wave to finish (agent-scope counter) computes the hinge sum + output.
__global__ __launch_bounds__(256) void k_S(
    const float* __restrict__ pmu, const float* __restrict__ psig,
    const int* __restrict__ x, const int* __restrict__ ctx,
    const int* __restrict__ negs, int C, int CN, int NEG, int KDIM,
    float* __restrict__ ws, float* __restrict__ out)
{
    const int tid = threadIdx.x;
    const int w = tid >> 6, lane = tid & 63;
    const int t = blockIdx.x * 4 + w;
    const int ntask = 2 + C + CN;
    float* Sbuf = ws + 4100;
    unsigned* cnt = (unsigned*)(ws + 4099);

    float acc = 0.f;
    const bool have = (t < ntask);
    if (have) {
        if (t == 0) {           // logdet = sum log sigma
#pragma unroll
            for (int k = 0; k < 16; ++k) acc += logf(ws[3072 + lane + 64 * k]);
        } else {
            int idx;
            if (t == 1)          idx = x[0];
            else if (t < 2 + C)  idx = ctx[t - 2];
            else                 idx = negs[t - 2 - C];
            const float4* m4  = (const float4*)(pmu  + (size_t)idx * CTXDIM);
            const float4* s4  = (const float4*)(psig + (size_t)idx * CTXDIM);
            const float4* mu4 = (const float4*)(ws + 2048);
            const float4* sg4 = (const float4*)(ws + 3072);
#pragma unroll
            for (int k = 0; k < 4; ++k) {
                const int i = lane + 64 * k;
                const float4 m  = m4[i];
                const float4 sv = s4[i];
                const float4 mu = mu4[i];
                const float4 sg = sg4[i];
                { const float s2 = sv.x*sv.x; const float d = m.x-mu.x; acc += (sg.x + d*d)/s2 + logf(s2); }
                { const float s2 = sv.y*sv.y; const float d = m.y-mu.y; acc += (sg.y + d*d)/s2 + logf(s2); }
                { const float s2 = sv.z*sv.z; const float d = m.z-mu.z; acc += (sg.z + d*d)/s2 + logf(s2); }
                { const float s2 = sv.w*sv.w; const float d = m.w-mu.w; acc += (sg.w + d*d)/s2 + logf(s2); }
            }
        }
#pragma unroll
        for (int m = 32; m >= 1; m >>= 1) acc += __shfl_xor(acc, m);
    }

    int win = 0;
    if (have && lane == 0) {
        __hip_atomic_store(&Sbuf[t], acc, __ATOMIC_RELAXED, __HIP_MEMORY_SCOPE_AGENT);
        const unsigned old = __hip_atomic_fetch_add(cnt, 1u,
                               __ATOMIC_ACQ_REL, __HIP_MEMORY_SCOPE_AGENT);
        win = (old == (unsigned)(ntask - 1));
    }
    win = __shfl(win, 0);
    if (win) {
        float lik = 0.f;
        for (int i = lane; i < CN; i += 64) {
            const float sn = __hip_atomic_load(&Sbuf[2 + C + i],
                               __ATOMIC_RELAXED, __HIP_MEMORY_SCOPE_AGENT);
            const float sp = __hip_atomic_load(&Sbuf[2 + i / NEG],
                               __ATOMIC_RELAXED, __HIP_MEMORY_SCOPE_AGENT);
            lik += fmaxf(0.f, 0.5f * (sn - sp) + 1.0f);   // kl_neg - kl_pos + 1
        }
#pragma unroll
        for (int m = 32; m >= 1; m >>= 1) lik += __shfl_xor(lik, m);
        if (lane == 0) {
            const float ld = __hip_atomic_load(&Sbuf[0],
                               __ATOMIC_RELAXED, __HIP_MEMORY_SCOPE_AGENT);
            const float sx = __hip_atomic_load(&Sbuf[1],
                               __ATOMIC_RELAXED, __HIP_MEMORY_SCOPE_AGENT);
            out[0] = lik - 0.5f * (sx - (float)KDIM - ld);  // - kl_prior
        }
    }
}

extern "C" void kernel_launch(void* const* d_in, const int* in_sizes, int n_in,
                              void* d_out, int out_size, void* d_ws, size_t ws_size,
                              hipStream_t stream) {
    const int*   x    = (const int*)d_in[0];
    const int*   ctx  = (const int*)d_in[1];
    const int*   negs = (const int*)d_in[2];
    const float* emb  = (const float*)d_in[3];
    const float* Mw   = (const float*)d_in[4];
    const float* Mb   = (const float*)d_in[5];
    const float* Uw   = (const float*)d_in[6];
    const float* Ub   = (const float*)d_in[7];
    const float* Ww   = (const float*)d_in[8];
    const float* Wb   = (const float*)d_in[9];
    const float* pmu  = (const float*)d_in[10];
    const float* psig = (const float*)d_in[11];
    float* ws  = (float*)d_ws;
    float* out = (float*)d_out;

    const int C    = in_sizes[1];          // 50
    const int CN   = in_sizes[2];          // 500
    const int NEG  = CN / C;               // 10
    const int KDIM = in_sizes[5];          // CTX = 1024

    k_h<<<CTXDIM / 4, 1024, 0, stream>>>(emb, Mw, Mb, x, ctx, C, ws);
    k_musig<<<512, 256, 0, stream>>>(Uw, Ub, Ww, Wb, ws);
    const int ntask = 2 + C + CN;
    k_S<<<(ntask + 3) / 4, 256, 0, stream>>>(pmu, psig, x, ctx, negs,
                                             C, CN, NEG, KDIM, ws, out);
}